// Round 2
// baseline (612.315 us; speedup 1.0000x reference)
//
#include <hip/hip_runtime.h>
#include <math.h>

#define DIM     2048
#define NEXP    64
#define CAP     128
#define NTOK    8192
#define NTILE   256            // 256 tiles of 32 tokens
#define KC      256            // K-chunk staged in LDS
#define NCH     (DIM/KC)       // 8 chunks
#define XWSTR   260            // row stride for xs/ws tiles (KC+4)
#define PSTR    68             // row stride for partial/logit tiles
#define RF      67108864       // floats per output region (S*E*C)
#define FBLK    4096           // fill blocks
#define FCH     8192           // f4 per fill block (128 KB)

typedef float vfloat4 __attribute__((ext_vector_type(4)));

// ---- 1. pure zero-fill, fillBufferAligned clone ----
// 256 threads, PLAIN f4 stores (no nt), contiguous 128 KB per block,
// no barrier, no patch, no LDS. This is the A/B against round-1's
// nt+barrier fill_patch: floor = 512 MiB / 6.3 TB/s ~ 85 us.
__global__ __launch_bounds__(256) void fill(float* __restrict__ out)
{
    vfloat4* o4 = reinterpret_cast<vfloat4*>(out);
    const vfloat4 z4 = {0.f, 0.f, 0.f, 0.f};
    const size_t base = (size_t)blockIdx.x * FCH + threadIdx.x;
    #pragma unroll
    for (int k = 0; k < 32; ++k)
        o4[base + (size_t)(k << 8)] = z4;     // 4 KB contiguous per step
    if (blockIdx.x == 0 && threadIdx.x == 0)
        out[134217728ull] = 0.0f;             // out[2*RF], past the f4 span
}

// ---- 2. gate GEMM + softmax/argmax/rank (unchanged, verified) ----
__global__ __launch_bounds__(512, 2) void gate(
    const float* __restrict__ x, const float* __restrict__ wg,
    int* __restrict__ expert_idx, float* __restrict__ gate_top,
    int* __restrict__ rank,
    float* __restrict__ me_partial, int* __restrict__ counts)
{
    __shared__ __align__(16) float smem[(32 + NEXP) * XWSTR]; // 99,840 B
    __shared__ float me_w[8 * NEXP];
    __shared__ int   cnt_w[8 * NEXP];
    __shared__ int   exp_s[32];

    float* xs = smem;                 // [32][XWSTR]
    float* ws = smem + 32 * XWSTR;    // [64][XWSTR]

    const int tid  = threadIdx.x;
    const int gb   = blockIdx.x;
    const int tok0 = gb * 32;
    const int sl   = tid >> 5;        // k-slice 0..15
    const int i    = tid & 31;
    const int tg   = i & 3;           // token group
    const int eg   = i >> 2;          // expert group 0..7
    const int kb   = sl * 16;         // slice's kk base within chunk

    float acc[8][8] = {};

    for (int ch = 0; ch < NCH; ++ch) {
        const int k0 = ch * KC;
        #pragma unroll
        for (int q = 0; q < 4; ++q) {
            int id = tid + (q << 9);
            int r = id >> 6, c = id & 63;
            float4 v = *(const float4*)(x + (size_t)(tok0 + r) * DIM + k0 + 4 * c);
            *(float4*)(&xs[r * XWSTR + 4 * c]) = v;
        }
        #pragma unroll
        for (int q = 0; q < 8; ++q) {
            int id = tid + (q << 9);
            int r = id >> 6, c = id & 63;
            float4 v = *(const float4*)(wg + (size_t)r * DIM + k0 + 4 * c);
            *(float4*)(&ws[r * XWSTR + 4 * c]) = v;
        }
        __syncthreads();

        #pragma unroll
        for (int q2 = 0; q2 < 4; ++q2) {
            const int kk = kb + 4 * q2;
            float4 xt[8], we[8];
            #pragma unroll
            for (int j = 0; j < 8; ++j)
                xt[j] = *(const float4*)(&xs[(tg + 4 * j) * XWSTR + kk]);
            #pragma unroll
            for (int m = 0; m < 8; ++m)
                we[m] = *(const float4*)(&ws[(eg + 8 * m) * XWSTR + kk]);
            #pragma unroll
            for (int j = 0; j < 8; ++j)
                #pragma unroll
                for (int m = 0; m < 8; ++m) {
                    acc[j][m] = fmaf(xt[j].x, we[m].x, acc[j][m]);
                    acc[j][m] = fmaf(xt[j].y, we[m].y, acc[j][m]);
                    acc[j][m] = fmaf(xt[j].z, we[m].z, acc[j][m]);
                    acc[j][m] = fmaf(xt[j].w, we[m].w, acc[j][m]);
                }
        }
        __syncthreads();
    }

    // ---- reduce 16 k-slices through LDS ----
    float* part = smem;                 // [8][32][PSTR]
    float* lgt  = smem + 8 * 32 * PSTR; // [32][PSTR]
    if (sl >= 8) {
        #pragma unroll
        for (int j = 0; j < 8; ++j)
            #pragma unroll
            for (int m = 0; m < 8; ++m)
                part[((sl - 8) * 32 + tg + 4 * j) * PSTR + eg + 8 * m] = acc[j][m];
    }
    __syncthreads();
    if (sl < 8) {
        #pragma unroll
        for (int j = 0; j < 8; ++j)
            #pragma unroll
            for (int m = 0; m < 8; ++m) {
                int idx = (sl * 32 + tg + 4 * j) * PSTR + eg + 8 * m;
                part[idx] += acc[j][m];
            }
    }
    __syncthreads();

    {
        int t  = tid >> 4;
        int e0 = (tid & 15) << 2;
        float4 a = {0, 0, 0, 0};
        #pragma unroll
        for (int s2 = 0; s2 < 8; ++s2) {
            float4 p = *(const float4*)(&part[(s2 * 32 + t) * PSTR + e0]);
            a.x += p.x; a.y += p.y; a.z += p.z; a.w += p.w;
        }
        *(float4*)(&lgt[t * PSTR + e0]) = a;
    }
    __syncthreads();

    // ---- softmax + argmax: 8 waves x 4 rows, lane = expert ----
    const int lane = tid & 63;
    const int wv   = tid >> 6;
    float me_acc  = 0.0f;
    int   cnt_acc = 0;
    #pragma unroll
    for (int r4 = 0; r4 < 4; ++r4) {
        int row = wv * 4 + r4;
        float v = lgt[row * PSTR + lane];
        float m = v; int mi = lane;
        #pragma unroll
        for (int off = 32; off > 0; off >>= 1) {
            float om  = __shfl_xor(m, off);
            int   omi = __shfl_xor(mi, off);
            if (om > m || (om == m && omi < mi)) { m = om; mi = omi; }
        }
        float ex = __expf(v - m);
        float sm = ex;
        #pragma unroll
        for (int off = 32; off > 0; off >>= 1) sm += __shfl_xor(sm, off);
        me_acc += ex / sm;
        if (lane == mi) {
            expert_idx[tok0 + row] = mi;
            gate_top[tok0 + row]   = 1.0f / sm;
            exp_s[row] = mi;
            ++cnt_acc;
        }
    }
    me_w[wv * NEXP + lane]  = me_acc;
    cnt_w[wv * NEXP + lane] = cnt_acc;
    __syncthreads();

    if (tid < 32) {   // within-tile rank (token order)
        int e = exp_s[tid];
        int rk = 0;
        for (int u = 0; u < tid; ++u) rk += (exp_s[u] == e) ? 1 : 0;
        rank[tok0 + tid] = rk;
    }
    if (tid < NEXP) {
        float ms = 0.f; int cs = 0;
        #pragma unroll
        for (int w = 0; w < 8; ++w) { ms += me_w[w * NEXP + tid]; cs += cnt_w[w * NEXP + tid]; }
        me_partial[gb * NEXP + tid] = ms;
        counts[gb * NEXP + tid]     = cs;
    }
}

// ---- 3. prefix + l_aux + compact per-token target position (unchanged) ----
__global__ __launch_bounds__(1024) void prefix_pos(
    const float* __restrict__ me_partial, const int* __restrict__ counts,
    const int* __restrict__ expert_idx, const int* __restrict__ rank,
    int* __restrict__ pos_g, float* __restrict__ laux)
{
    __shared__ int   bo_l[NTILE * NEXP];   // 64 KB exclusive offsets
    __shared__ int   cnt_l[16 * NEXP];
    __shared__ float me_l[16 * NEXP];
    __shared__ int   cnt_tot[NEXP];
    __shared__ float me_tot[NEXP];

    const int tid = threadIdx.x;
    const int e   = tid & 63;
    const int g   = tid >> 6;          // 0..15

    int cs = 0; float ms = 0.f;
    #pragma unroll
    for (int i = 0; i < 16; ++i) {
        int t = g * 16 + i;
        cs += counts[t * NEXP + e];
        ms += me_partial[t * NEXP + e];
    }
    cnt_l[g * NEXP + e] = cs;
    me_l[g * NEXP + e]  = ms;
    __syncthreads();

    if (g == 0) {
        int run = 0; float mt = 0.f;
        #pragma unroll
        for (int i = 0; i < 16; ++i) {
            int c = cnt_l[i * NEXP + e];
            cnt_l[i * NEXP + e] = run;
            run += c;
            mt  += me_l[i * NEXP + e];
        }
        cnt_tot[e] = run;
        me_tot[e]  = mt;
    }
    __syncthreads();

    int run = cnt_l[g * NEXP + e];
    #pragma unroll
    for (int i = 0; i < 16; ++i) {
        int t = g * 16 + i;
        bo_l[t * NEXP + e] = run;
        run += counts[t * NEXP + e];
    }
    __syncthreads();

    if (tid < NEXP) {
        float v = (me_tot[e] / (float)NTOK) * ((float)cnt_tot[e] / (float)NTOK);
        #pragma unroll
        for (int off = 32; off > 0; off >>= 1) v += __shfl_xor(v, off);
        if (e == 0) laux[0] = v * (float)NEXP;   // mean(me*ce)*E*E == sum*E
    }

    #pragma unroll
    for (int ii = 0; ii < 8; ++ii) {
        int s  = tid + (ii << 10);
        int ex = expert_idx[s];
        int loc = bo_l[(s >> 5) * NEXP + ex] + rank[s];
        // final float index in out[], or -1 if dropped (max RF, fits int)
        pos_g[s] = (loc < CAP) ? (1 + s * (NEXP * CAP) + ex * CAP + loc) : -1;
    }
}

// ---- 4. scatter patch: 8192 tokens x 2 stores, spread over 128 blocks ----
// Latency-bound by design: every CU gets work, each thread issues at most
// two independent 4 B stores into freshly-zeroed memory. Runs after fill
// (stream order), so no intra-kernel ordering is needed.
__global__ __launch_bounds__(64) void patch(
    const int* __restrict__ pos_g, const float* __restrict__ gate_top,
    const float* __restrict__ laux, float* __restrict__ out)
{
    const int s = blockIdx.x * 64 + threadIdx.x;   // 128 blocks x 64 = 8192
    const int p = pos_g[s];
    if (p >= 0) {
        out[(size_t)p]      = gate_top[s];   // combine
        out[(size_t)p + RF] = 1.0f;          // dispatch
    }
    if (s == 0) out[0] = laux[0];            // l_aux
}

extern "C" void kernel_launch(void* const* d_in, const int* in_sizes, int n_in,
                              void* d_out, int out_size, void* d_ws, size_t ws_size,
                              hipStream_t stream)
{
    const float* x  = (const float*)d_in[0];
    const float* wg = (const float*)d_in[1];
    float* out = (float*)d_out;

    char* ws = (char*)d_ws;
    int*   expert_idx = (int*)  (ws);             // 32 KB
    float* gate_top   = (float*)(ws + 32768);     // 32 KB
    int*   rank       = (int*)  (ws + 65536);     // 32 KB
    float* me_partial = (float*)(ws + 98304);     // 64 KB
    int*   counts     = (int*)  (ws + 163840);    // 64 KB
    int*   pos_g      = (int*)  (ws + 229376);    // 32 KB
    float* laux       = (float*)(ws + 262144);    // 4 B   (total 256 KB + 4)

    fill<<<FBLK, 256, 0, stream>>>(out);
    gate<<<NTILE, 512, 0, stream>>>(x, wg, expert_idx, gate_top, rank,
                                    me_partial, counts);
    prefix_pos<<<1, 1024, 0, stream>>>(me_partial, counts, expert_idx, rank,
                                       pos_g, laux);
    patch<<<128, 64, 0, stream>>>(pos_g, gate_top, laux, out);
}

// Round 3
// 606.166 us; speedup vs baseline: 1.0101x; 1.0101x over previous
//
#include <hip/hip_runtime.h>
#include <math.h>

#define DIM     2048
#define NEXP    64
#define CAP     128
#define NTOK    8192
#define NTILE   256            // 256 tiles of 32 tokens
#define KC      256            // K-chunk staged in LDS
#define NCH     (DIM/KC)       // 8 chunks
#define XWSTR   260            // row stride for xs/ws tiles (KC+4)
#define PSTR    68             // row stride for partial/logit tiles
#define RF      67108864       // floats per output region (S*E*C)

typedef float vfloat4 __attribute__((ext_vector_type(4)));

// ---- 1. gate GEMM with the 512 MiB zero-fill riding the same kernel ----
// Key difference vs R0's fused attempt: chunk barriers are RAW s_barrier +
// lgkmcnt(0)-only waits (inline asm), never __syncthreads(). The compiler's
// auto-waitcnt before each ds_write waits only for the staging loads
// (in-order vmcnt lets the 32 younger fill stores stay outstanding), so the
// store pipe NEVER drains inside the loop: the fill streams at wire speed
// for the whole kernel and the GEMM executes inside its shadow.
__global__ __launch_bounds__(512, 2) void gate_fill(
    const float* __restrict__ x, const float* __restrict__ wg,
    float* __restrict__ out,
    int* __restrict__ expert_idx, float* __restrict__ gate_top,
    int* __restrict__ rank,
    float* __restrict__ me_partial, int* __restrict__ counts)
{
    __shared__ __align__(16) float smem[(32 + NEXP) * XWSTR]; // 99,840 B
    __shared__ float me_w[8 * NEXP];
    __shared__ int   cnt_w[8 * NEXP];
    __shared__ int   exp_s[32];

    float* xs = smem;                 // [32][XWSTR]
    float* ws = smem + 32 * XWSTR;    // [64][XWSTR]

    const int tid  = threadIdx.x;
    const int gb   = blockIdx.x;
    const int tok0 = gb * 32;
    const int sl   = tid >> 5;        // k-slice 0..15
    const int i    = tid & 31;
    const int tg   = i & 3;           // token group
    const int eg   = i >> 2;          // expert group 0..7
    const int kb   = sl * 16;         // slice's kk base within chunk

    vfloat4* o4 = reinterpret_cast<vfloat4*>(out);
    const vfloat4 z4 = {0.f, 0.f, 0.f, 0.f};
    if (gb == 0 && tid == 0)
        out[134217728ull] = 0.0f;     // out[2*RF], past the f4 span

    float acc[8][8] = {};

    for (int ch = 0; ch < NCH; ++ch) {
        const int k0 = ch * KC;
        // staging loads into registers FIRST (GEMM critical path)...
        float4 xv[4], wv[8];
        #pragma unroll
        for (int q = 0; q < 4; ++q) {
            int id = tid + (q << 9);
            int r = id >> 6, c = id & 63;
            xv[q] = *(const float4*)(x + (size_t)(tok0 + r) * DIM + k0 + 4 * c);
        }
        #pragma unroll
        for (int q = 0; q < 8; ++q) {
            int id = tid + (q << 9);
            int r = id >> 6, c = id & 63;
            wv[q] = *(const float4*)(wg + (size_t)r * DIM + k0 + 4 * c);
        }
        // ...then this chunk's 32 fill stores (fire-and-forget; they stay
        // outstanding across the raw barriers below and pace the kernel
        // at HBM write wire speed).
        {
            size_t base = (size_t)gb * 131072 + (size_t)(ch << 14) + tid;
            #pragma unroll
            for (int k = 0; k < 32; ++k)
                __builtin_nontemporal_store(z4, &o4[base + (size_t)(k << 9)]);
        }
        // LDS staging writes (compiler waits vmcnt only down to the loads,
        // leaving the younger stores in flight).
        #pragma unroll
        for (int q = 0; q < 4; ++q) {
            int id = tid + (q << 9);
            int r = id >> 6, c = id & 63;
            *(float4*)(&xs[r * XWSTR + 4 * c]) = xv[q];
        }
        #pragma unroll
        for (int q = 0; q < 8; ++q) {
            int id = tid + (q << 9);
            int r = id >> 6, c = id & 63;
            *(float4*)(&ws[r * XWSTR + 4 * c]) = wv[q];
        }
        // raw barrier: LDS visibility only -- NO vmcnt drain
        __builtin_amdgcn_sched_barrier(0);
        asm volatile("s_waitcnt lgkmcnt(0)" ::: "memory");
        __builtin_amdgcn_sched_barrier(0);
        __builtin_amdgcn_s_barrier();
        __builtin_amdgcn_sched_barrier(0);

        #pragma unroll
        for (int q2 = 0; q2 < 4; ++q2) {
            const int kk = kb + 4 * q2;
            float4 xt[8], we[8];
            #pragma unroll
            for (int j = 0; j < 8; ++j)
                xt[j] = *(const float4*)(&xs[(tg + 4 * j) * XWSTR + kk]);
            #pragma unroll
            for (int m = 0; m < 8; ++m)
                we[m] = *(const float4*)(&ws[(eg + 8 * m) * XWSTR + kk]);
            #pragma unroll
            for (int j = 0; j < 8; ++j)
                #pragma unroll
                for (int m = 0; m < 8; ++m) {
                    acc[j][m] = fmaf(xt[j].x, we[m].x, acc[j][m]);
                    acc[j][m] = fmaf(xt[j].y, we[m].y, acc[j][m]);
                    acc[j][m] = fmaf(xt[j].z, we[m].z, acc[j][m]);
                    acc[j][m] = fmaf(xt[j].w, we[m].w, acc[j][m]);
                }
        }

        // trailing raw barrier: all waves done READING xs/ws before next
        // chunk's staging overwrites them. Again no vmcnt drain.
        __builtin_amdgcn_sched_barrier(0);
        asm volatile("s_waitcnt lgkmcnt(0)" ::: "memory");
        __builtin_amdgcn_sched_barrier(0);
        __builtin_amdgcn_s_barrier();
        __builtin_amdgcn_sched_barrier(0);
    }

    // ---- reduce 16 k-slices through LDS (plain barriers from here on;
    // the first one drains the store backlog = remaining fill wire time) ----
    float* part = smem;                 // [8][32][PSTR]
    float* lgt  = smem + 8 * 32 * PSTR; // [32][PSTR]
    if (sl >= 8) {
        #pragma unroll
        for (int j = 0; j < 8; ++j)
            #pragma unroll
            for (int m = 0; m < 8; ++m)
                part[((sl - 8) * 32 + tg + 4 * j) * PSTR + eg + 8 * m] = acc[j][m];
    }
    __syncthreads();
    if (sl < 8) {
        #pragma unroll
        for (int j = 0; j < 8; ++j)
            #pragma unroll
            for (int m = 0; m < 8; ++m) {
                int idx = (sl * 32 + tg + 4 * j) * PSTR + eg + 8 * m;
                part[idx] += acc[j][m];
            }
    }
    __syncthreads();

    {
        int t  = tid >> 4;
        int e0 = (tid & 15) << 2;
        float4 a = {0, 0, 0, 0};
        #pragma unroll
        for (int s2 = 0; s2 < 8; ++s2) {
            float4 p = *(const float4*)(&part[(s2 * 32 + t) * PSTR + e0]);
            a.x += p.x; a.y += p.y; a.z += p.z; a.w += p.w;
        }
        *(float4*)(&lgt[t * PSTR + e0]) = a;
    }
    __syncthreads();

    // ---- softmax + argmax: 8 waves x 4 rows, lane = expert ----
    const int lane = tid & 63;
    const int wv2  = tid >> 6;
    float me_acc  = 0.0f;
    int   cnt_acc = 0;
    #pragma unroll
    for (int r4 = 0; r4 < 4; ++r4) {
        int row = wv2 * 4 + r4;
        float v = lgt[row * PSTR + lane];
        float m = v; int mi = lane;
        #pragma unroll
        for (int off = 32; off > 0; off >>= 1) {
            float om  = __shfl_xor(m, off);
            int   omi = __shfl_xor(mi, off);
            if (om > m || (om == m && omi < mi)) { m = om; mi = omi; }
        }
        float ex = __expf(v - m);
        float sm = ex;
        #pragma unroll
        for (int off = 32; off > 0; off >>= 1) sm += __shfl_xor(sm, off);
        me_acc += ex / sm;
        if (lane == mi) {
            expert_idx[tok0 + row] = mi;
            gate_top[tok0 + row]   = 1.0f / sm;
            exp_s[row] = mi;
            ++cnt_acc;
        }
    }
    me_w[wv2 * NEXP + lane]  = me_acc;
    cnt_w[wv2 * NEXP + lane] = cnt_acc;
    __syncthreads();

    if (tid < 32) {   // within-tile rank (token order)
        int e = exp_s[tid];
        int rk = 0;
        for (int u = 0; u < tid; ++u) rk += (exp_s[u] == e) ? 1 : 0;
        rank[tok0 + tid] = rk;
    }
    if (tid < NEXP) {
        float ms = 0.f; int cs = 0;
        #pragma unroll
        for (int w = 0; w < 8; ++w) { ms += me_w[w * NEXP + tid]; cs += cnt_w[w * NEXP + tid]; }
        me_partial[gb * NEXP + tid] = ms;
        counts[gb * NEXP + tid]     = cs;
    }
}

// ---- 2. prefix + l_aux + compact per-token target position (unchanged) ----
__global__ __launch_bounds__(1024) void prefix_pos(
    const float* __restrict__ me_partial, const int* __restrict__ counts,
    const int* __restrict__ expert_idx, const int* __restrict__ rank,
    int* __restrict__ pos_g, float* __restrict__ laux)
{
    __shared__ int   bo_l[NTILE * NEXP];   // 64 KB exclusive offsets
    __shared__ int   cnt_l[16 * NEXP];
    __shared__ float me_l[16 * NEXP];
    __shared__ int   cnt_tot[NEXP];
    __shared__ float me_tot[NEXP];

    const int tid = threadIdx.x;
    const int e   = tid & 63;
    const int g   = tid >> 6;          // 0..15

    int cs = 0; float ms = 0.f;
    #pragma unroll
    for (int i = 0; i < 16; ++i) {
        int t = g * 16 + i;
        cs += counts[t * NEXP + e];
        ms += me_partial[t * NEXP + e];
    }
    cnt_l[g * NEXP + e] = cs;
    me_l[g * NEXP + e]  = ms;
    __syncthreads();

    if (g == 0) {
        int run = 0; float mt = 0.f;
        #pragma unroll
        for (int i = 0; i < 16; ++i) {
            int c = cnt_l[i * NEXP + e];
            cnt_l[i * NEXP + e] = run;
            run += c;
            mt  += me_l[i * NEXP + e];
        }
        cnt_tot[e] = run;
        me_tot[e]  = mt;
    }
    __syncthreads();

    int run = cnt_l[g * NEXP + e];
    #pragma unroll
    for (int i = 0; i < 16; ++i) {
        int t = g * 16 + i;
        bo_l[t * NEXP + e] = run;
        run += counts[t * NEXP + e];
    }
    __syncthreads();

    if (tid < NEXP) {
        float v = (me_tot[e] / (float)NTOK) * ((float)cnt_tot[e] / (float)NTOK);
        #pragma unroll
        for (int off = 32; off > 0; off >>= 1) v += __shfl_xor(v, off);
        if (e == 0) laux[0] = v * (float)NEXP;   // mean(me*ce)*E*E == sum*E
    }

    #pragma unroll
    for (int ii = 0; ii < 8; ++ii) {
        int s  = tid + (ii << 10);
        int ex = expert_idx[s];
        int loc = bo_l[(s >> 5) * NEXP + ex] + rank[s];
        // final float index in out[], or -1 if dropped (max RF, fits int)
        pos_g[s] = (loc < CAP) ? (1 + s * (NEXP * CAP) + ex * CAP + loc) : -1;
    }
}

// ---- 3. scatter patch: 8192 tokens x 2 stores, spread over 128 blocks ----
__global__ __launch_bounds__(64) void patch(
    const int* __restrict__ pos_g, const float* __restrict__ gate_top,
    const float* __restrict__ laux, float* __restrict__ out)
{
    const int s = blockIdx.x * 64 + threadIdx.x;   // 128 blocks x 64 = 8192
    const int p = pos_g[s];
    if (p >= 0) {
        out[(size_t)p]      = gate_top[s];   // combine
        out[(size_t)p + RF] = 1.0f;          // dispatch
    }
    if (s == 0) out[0] = laux[0];            // l_aux
}

extern "C" void kernel_launch(void* const* d_in, const int* in_sizes, int n_in,
                              void* d_out, int out_size, void* d_ws, size_t ws_size,
                              hipStream_t stream)
{
    const float* x  = (const float*)d_in[0];
    const float* wg = (const float*)d_in[1];
    float* out = (float*)d_out;

    char* ws = (char*)d_ws;
    int*   expert_idx = (int*)  (ws);             // 32 KB
    float* gate_top   = (float*)(ws + 32768);     // 32 KB
    int*   rank       = (int*)  (ws + 65536);     // 32 KB
    float* me_partial = (float*)(ws + 98304);     // 64 KB
    int*   counts     = (int*)  (ws + 163840);    // 64 KB
    int*   pos_g      = (int*)  (ws + 229376);    // 32 KB
    float* laux       = (float*)(ws + 262144);    // 4 B   (total 256 KB + 4)

    gate_fill<<<NTILE, 512, 0, stream>>>(x, wg, out, expert_idx, gate_top,
                                         rank, me_partial, counts);
    prefix_pos<<<1, 1024, 0, stream>>>(me_partial, counts, expert_idx, rank,
                                       pos_g, laux);
    patch<<<128, 64, 0, stream>>>(pos_g, gate_top, laux, out);
}